// Round 9
// baseline (247.304 us; speedup 1.0000x reference)
//
#include <hip/hip_runtime.h>
#include <math.h>

// Problem constants
#define B_   32
#define T0_  256
#define J_   512
#define V_   1024
#define Q_   32
#define L_   20
#define P_   241
#define NEG_ (-1e9f)

typedef __attribute__((ext_vector_type(8))) _Float16 half8;
typedef __attribute__((ext_vector_type(4))) _Float16 half4v;
typedef __attribute__((ext_vector_type(4))) float f32x4;

// ---------------------------------------------------------------------------
// 1-pass fp16 MFMA GEMM: C[m][n] = sum_k AH[m][k] * BH[n][k]
// Tile 128x64, 4 waves (2x2), wave tile 64x32: FM=4, FN=2 -> LDS-read
// bytes/MFMA/lane = 16*(4+2)/8 = 12B (was 16B at 2x2). LDS-read BW is the
// structural bound (820 B/cyc demand vs 256 avail at 2x2 => ~31% ceiling;
// 4x2 => ~42%). KCH=128 halves barrier count vs KCH=64.
// A row view: arow = (m/TDIV)*SB + S0 + (m%TDIV)*TMUL, row stride ASTR
// (im2col for stride-2 conv: TMUL=2, ASTR=512).
// blockIdx.z = split-K slice (k in [z*KLEN, (z+1)*KLEN)).
// EPI: 0 = +bias -> fp16 (orow map); 2 = plain f32 (stride NS);
//      3 = f32 partials [z][MP][512].
// LDS row stride KCH+8 halves: stride-scramble gives uniform-8 bank access
// (the b128-wave64 structural minimum) on both reads and writes.
// Staging: static register arrays, fixed plane pointers (R6 scratch lesson).
// Grids kept >= 2 blocks/CU everywhere the shape allows (R3/R5/R7 lesson).
// ---------------------------------------------------------------------------
template<int KCH, int EPI>
__global__ __launch_bounds__(256) void g1p(
    const _Float16* __restrict__ AH, const _Float16* __restrict__ BH,
    const float* __restrict__ bias,
    _Float16* __restrict__ outH, float* __restrict__ outF,
    int MROWS, int TDIV, int SB, int S0, int TMUL, int ASTR, int BSTR,
    int KLEN, int MP, int OSB, int OS0, int NS) {
  constexpr int BM = 128, FM = 4, FN = 2;
  constexpr int LSTR = KCH + 8;
  constexpr int AW = KCH / 2;           // halves per thread, A (2 thr/row)
  constexpr int AU = AW / 8;
  constexpr int BW = KCH / 4;           // halves per thread, B (4 thr/row)
  constexpr int BU = BW / 8;
  __shared__ _Float16 aS[BM * LSTR], bS[64 * LSTR];

  const int tid = threadIdx.x;
  const int m0 = blockIdx.x * BM, n0 = blockIdx.y * 64;
  const int k00 = blockIdx.z * KLEN;
  const int wave = tid >> 6, lane = tid & 63;
  const int wm = (wave >> 1) * 64, wn = (wave & 1) * 32;
  const int fr = lane & 15, fq = lane >> 4;

  const int arow = tid >> 1, acol = (tid & 1) * AW;
  const int brow = tid >> 2, bcol = (tid & 3) * BW;

  const int gm = m0 + arow;
  const bool mval = gm < MROWS;
  const int b2g = gm / TDIV, t2g = gm - b2g * TDIV;
  const size_t aoff = (size_t)(b2g * SB + S0 + t2g * TMUL) * (size_t)ASTR;
  const size_t boff = (size_t)(n0 + brow) * (size_t)BSTR;

  f32x4 acc[FM][FN];
  #pragma unroll
  for (int i = 0; i < FM; ++i)
    #pragma unroll
    for (int j = 0; j < FN; ++j) acc[i][j] = (f32x4)0.f;

  half8 z;
  #pragma unroll
  for (int j = 0; j < 8; ++j) z[j] = (_Float16)0.f;

  half8 rA[AU], rB[BU];
  auto load = [&](int it) {
    const int k = k00 + it * KCH;
    if (mval) {
      #pragma unroll
      for (int i = 0; i < AU; ++i)
        rA[i] = *reinterpret_cast<const half8*>(&AH[aoff + k + acol + i * 8]);
    } else {
      #pragma unroll
      for (int i = 0; i < AU; ++i) rA[i] = z;
    }
    #pragma unroll
    for (int i = 0; i < BU; ++i)
      rB[i] = *reinterpret_cast<const half8*>(&BH[boff + k + bcol + i * 8]);
  };

  load(0);
  const int NI = KLEN / KCH;

  for (int it = 0; it < NI; ++it) {
    __syncthreads();
    #pragma unroll
    for (int i = 0; i < AU; ++i)
      *reinterpret_cast<half8*>(&aS[arow * LSTR + acol + i * 8]) = rA[i];
    #pragma unroll
    for (int i = 0; i < BU; ++i)
      *reinterpret_cast<half8*>(&bS[brow * LSTR + bcol + i * 8]) = rB[i];
    __syncthreads();
    if (it + 1 < NI) load(it + 1);

    #pragma unroll
    for (int ks = 0; ks < KCH / 32; ++ks) {
      const int ko = ks * 32 + fq * 8;
      half8 a[FM], b[FN];
      #pragma unroll
      for (int mt = 0; mt < FM; ++mt)
        a[mt] = *reinterpret_cast<const half8*>(&aS[(wm + mt * 16 + fr) * LSTR + ko]);
      #pragma unroll
      for (int nt = 0; nt < FN; ++nt)
        b[nt] = *reinterpret_cast<const half8*>(&bS[(wn + nt * 16 + fr) * LSTR + ko]);
      #pragma unroll
      for (int mt = 0; mt < FM; ++mt)
        #pragma unroll
        for (int nt = 0; nt < FN; ++nt)
          acc[mt][nt] = __builtin_amdgcn_mfma_f32_16x16x32_f16(a[mt], b[nt], acc[mt][nt], 0, 0, 0);
    }
  }

  // Epilogue. C layout: col = lane&15 (n), row = fq*4 + reg (m).
  #pragma unroll
  for (int mt = 0; mt < FM; ++mt) {
    const int mB2 = m0 + wm + mt * 16 + fq * 4;
    #pragma unroll
    for (int nt = 0; nt < FN; ++nt) {
      const int n = n0 + wn + nt * 16 + fr;
      f32x4 c = acc[mt][nt];
      #pragma unroll
      for (int r = 0; r < 4; ++r) {
        const int m = mB2 + r;
        if (m < MROWS) {
          if (EPI == 3) {
            outF[((size_t)blockIdx.z * MP + m) * 512 + n] = c[r];
          } else if (EPI == 2) {
            outF[(size_t)m * NS + n] = c[r];
          } else {
            float x = c[r] + bias[n];
            const int bb2 = m / TDIV, tt2 = m - bb2 * TDIV;
            const int orow = bb2 * OSB + OS0 + tt2;
            outH[(size_t)orow * 512 + n] = (_Float16)x;
          }
        }
      }
    }
  }
}

// ---------------------------------------------------------------------------
// Split-K reduce: out(orow) = relu(sum_z part[z][m] + bias) -> fp16
// ---------------------------------------------------------------------------
__global__ __launch_bounds__(256) void reduce_kernel(
    const float* __restrict__ part, const float* __restrict__ bias,
    _Float16* __restrict__ outH,
    int kS, int MROWS, int MP, int Tl, int Poff) {
  int idx = blockIdx.x * 256 + threadIdx.x;
  if (idx >= MROWS * 512) return;
  int m = idx >> 9, n = idx & 511;
  float s = 0.f;
  for (int ks = 0; ks < kS; ++ks) s += part[((size_t)ks * MP + m) * 512 + n];
  float x = fmaxf(s + bias[n], 0.f);
  int b2 = m / Tl, t2 = m - b2 * Tl;
  int orow = b2 * P_ + Poff + t2;
  outH[(size_t)orow * 512 + n] = (_Float16)x;
}

// ---------------------------------------------------------------------------
// Unified prep: video cvt (2097152 f4), fc_w (131072), pw (65536),
// words (81920), conv_w repack (1572864 e-units). One launch, grid-stride.
// ---------------------------------------------------------------------------
#define PREP_C0 2097152
#define PREP_C1 2228224
#define PREP_C2 2293760
#define PREP_C3 2375680
#define PREP_C4 3948544
__global__ __launch_bounds__(256) void prep_kernel(
    const float* __restrict__ video, const float* __restrict__ fcw,
    const float* __restrict__ pw, const float* __restrict__ words,
    const float* __restrict__ cw,
    _Float16* __restrict__ videoH, _Float16* __restrict__ fcwH,
    _Float16* __restrict__ pwH, _Float16* __restrict__ wordsH,
    _Float16* __restrict__ cwH) {
  for (int u = blockIdx.x * 256 + threadIdx.x; u < PREP_C4; u += 2048 * 256) {
    if (u < PREP_C3) {
      const float* src; _Float16* dst; int off;
      if (u < PREP_C0)      { src = video; dst = videoH; off = u; }
      else if (u < PREP_C1) { src = fcw;   dst = fcwH;   off = u - PREP_C0; }
      else if (u < PREP_C2) { src = pw;    dst = pwH;    off = u - PREP_C1; }
      else                  { src = words; dst = wordsH; off = u - PREP_C2; }
      float4 v = *reinterpret_cast<const float4*>(&src[(size_t)off * 4]);
      half4v h;
      h[0] = (_Float16)v.x; h[1] = (_Float16)v.y;
      h[2] = (_Float16)v.z; h[3] = (_Float16)v.w;
      *reinterpret_cast<half4v*>(&dst[(size_t)off * 4]) = h;
    } else {
      int e = u - PREP_C3;
      float4 v = *reinterpret_cast<const float4*>(&cw[(size_t)e * 4]);
      int li = e >> 18, rem = e & 262143, o = rem >> 9, i = rem & 511;
      size_t rb = ((size_t)(li * 512 + o)) * 2048 + i;
      cwH[rb]        = (_Float16)v.x;
      cwH[rb + 512]  = (_Float16)v.y;
      cwH[rb + 1024] = (_Float16)v.z;
      cwH[rb + 1536] = (_Float16)v.w;
    }
  }
}

// ---------------------------------------------------------------------------
// Row L2 norms of f_all (fp16)
// ---------------------------------------------------------------------------
__global__ __launch_bounds__(256) void fnorm_kernel(
    const _Float16* __restrict__ fH, float* __restrict__ fn) {
  int gw = (blockIdx.x * 256 + threadIdx.x) >> 6;
  int lane = threadIdx.x & 63;
  if (gw >= B_ * P_) return;
  half8 h = *reinterpret_cast<const half8*>(&fH[(size_t)gw * 512 + lane * 8]);
  float s = 0.f;
  #pragma unroll
  for (int j = 0; j < 8; ++j) {
    float x = (float)h[j];
    s += x * x;
  }
  #pragma unroll
  for (int off = 32; off; off >>= 1) s += __shfl_xor(s, off);
  if (lane == 0) fn[gw] = sqrtf(s);
}

// ---------------------------------------------------------------------------
// Per-query word Gram matrices (f32 words input)
// ---------------------------------------------------------------------------
__global__ __launch_bounds__(256) void gram_kernel(
    const float* __restrict__ words, float* __restrict__ gram) {
  __shared__ float wsh[L_][513];
  int q = blockIdx.x, tid = threadIdx.x;
  for (int idx = tid; idx < L_ * 512; idx += 256)
    wsh[idx >> 9][idx & 511] = words[(size_t)q * L_ * J_ + idx];
  __syncthreads();
  for (int pr = tid; pr < L_ * L_; pr += 256) {
    int l = pr / L_, l2 = pr % L_;
    float sum = 0.f;
    for (int d = 0; d < J_; ++d) sum += wsh[l][d] * wsh[l2][d];
    gram[q * L_ * L_ + pr] = sum;
  }
}

// ---------------------------------------------------------------------------
// Softmax + cosine-sim epilogue per (q,b,p); positive_map fused (q==b rows).
// ---------------------------------------------------------------------------
__global__ __launch_bounds__(256) void sim_kernel(
    const float* __restrict__ logits, const float* __restrict__ gram,
    const float* __restrict__ fnorm, float* __restrict__ score,
    float* __restrict__ out) {
  int idx = blockIdx.x * 256 + threadIdx.x;
  if (idx >= Q_ * B_ * P_) return;
  int q = idx / (B_ * P_);
  int r = idx - q * (B_ * P_);
  const float* lg = &logits[(size_t)r * (Q_ * L_) + q * L_];
  float raw[L_], e[L_];
  float m = -1e30f;
  #pragma unroll
  for (int l = 0; l < L_; ++l) { raw[l] = lg[l]; m = fmaxf(m, raw[l]); }
  float s = 0.f;
  #pragma unroll
  for (int l = 0; l < L_; ++l) { e[l] = __expf(raw[l] - m); s += e[l]; }
  float inv = 1.f / s;
  float fvs = 0.f;
  #pragma unroll
  for (int l = 0; l < L_; ++l) fvs += e[l] * raw[l];
  fvs *= inv;
  const float* G = &gram[q * L_ * L_];
  float vn2 = 0.f;
  for (int l = 0; l < L_; ++l) {
    float acc = 0.f;
    #pragma unroll
    for (int l2 = 0; l2 < L_; ++l2) acc += e[l2] * G[l * L_ + l2];
    vn2 += e[l] * acc;
  }
  vn2 *= inv * inv;
  float fn = fnorm[r] + 1e-8f;
  float vn = sqrtf(fmaxf(vn2, 0.f)) + 1e-8f;
  float val = fvs / (fn * vn);
  score[idx] = val;
  int b = r / P_;
  if (b == q) out[1 + r] = val;   // positive_map (r = b*P + p)
}

// ---------------------------------------------------------------------------
// Greedy NMS
// ---------------------------------------------------------------------------
__global__ __launch_bounds__(256) void nms_kernel(
    const float* __restrict__ score, const float* __restrict__ iou,
    const float* __restrict__ lam, float* __restrict__ smat) {
  int wid = (blockIdx.x * 256 + threadIdx.x) >> 6;
  int lane = threadIdx.x & 63;
  if (wid >= Q_ * B_) return;
  const float* srow = &score[(size_t)wid * P_];
  float s[4];
  #pragma unroll
  for (int i = 0; i < 4; ++i) {
    int p = lane + 64 * i;
    s[i] = (p < P_) ? srow[p] : NEG_;
  }
  float lamv = lam[0];
  float acc = 0.f, wgt = 1.f;
  for (int k = 0; k < 5; ++k) {
    float bv = NEG_ * 2.f; int bi = 1 << 30;
    #pragma unroll
    for (int i = 0; i < 4; ++i) {
      int p = lane + 64 * i;
      if (s[i] > bv) { bv = s[i]; bi = p; }
    }
    for (int off = 32; off; off >>= 1) {
      float ov = __shfl_xor(bv, off);
      int oi = __shfl_xor(bi, off);
      if (ov > bv || (ov == bv && oi < bi)) { bv = ov; bi = oi; }
    }
    acc += bv * wgt;
    wgt *= lamv;
    const float* irow = &iou[(size_t)bi * P_];
    #pragma unroll
    for (int i = 0; i < 4; ++i) {
      int p = lane + 64 * i;
      if (p < P_ && irow[p] > 0.7f) s[i] = NEG_;
      if (p == bi) s[i] = NEG_;
    }
  }
  if (lane == 0) smat[wid] = acc * 0.2f;
}

// ---------------------------------------------------------------------------
// diag margin loss
// ---------------------------------------------------------------------------
__global__ __launch_bounds__(1024) void loss_kernel(
    const float* __restrict__ smat, float* __restrict__ out) {
  __shared__ float sm[B_][B_ + 1];
  __shared__ float red[16];
  int tid = threadIdx.x;
  sm[tid >> 5][tid & 31] = smat[tid];
  __syncthreads();
  int i = tid >> 5, j = tid & 31;
  float val = 0.f;
  if (i != j) {
    float sij = sm[i][j];
    val = fmaxf(0.f, 0.2f + sij - sm[i][i]) + fmaxf(0.f, 0.2f + sij - sm[j][j]);
  }
  #pragma unroll
  for (int off = 32; off; off >>= 1) val += __shfl_xor(val, off);
  if ((tid & 63) == 0) red[tid >> 6] = val;
  __syncthreads();
  if (tid == 0) {
    float t = 0.f;
    #pragma unroll
    for (int w = 0; w < 16; ++w) t += red[w];
    out[0] = t / 32.f;
  }
}

extern "C" void kernel_launch(void* const* d_in, const int* in_sizes, int n_in,
                              void* d_out, int out_size, void* d_ws, size_t ws_size,
                              hipStream_t stream) {
  const float* video  = (const float*)d_in[0];
  const float* words  = (const float*)d_in[1];
  // d_in[2] = w_masks: all-ones by construction, unused
  const float* lam    = (const float*)d_in[3];
  const float* iou    = (const float*)d_in[4];
  const float* fc_w   = (const float*)d_in[5];
  const float* fc_b   = (const float*)d_in[6];
  const float* conv_w = (const float*)d_in[7];
  const float* conv_b = (const float*)d_in[8];
  const float* pw     = (const float*)d_in[9];
  const float* pb     = (const float*)d_in[10];
  float* out = (float*)d_out;

  // Workspace layout (bytes) — same footprint as R8 (proven). Split-K
  // partials alias the logits region (written later).
  char* base = (char*)d_ws;
  _Float16* videoH= (_Float16*)(base + 0);              // 8192*1024 (16.78 MB)
  _Float16* fcoH  = (_Float16*)(base + 16777216);       // 8192*512  (8.39 MB)
  _Float16* pyrH  = (_Float16*)(base + 25165824);       // 7712*512  (7.90 MB)
  _Float16* fallH = (_Float16*)(base + 33062912);       // 7712*512  (7.90 MB)
  _Float16* cwH   = (_Float16*)(base + 40960000);       // 6*512*2048 (12.58 MB)
  _Float16* fcwH  = (_Float16*)(base + 53542912);       // 512*1024  (1.05 MB)
  _Float16* pwH   = (_Float16*)(base + 54591488);       // 512*512   (0.52 MB)
  _Float16* wordsH= (_Float16*)(base + 55115776);       // 32*20*512 (0.66 MB)
  float*    logits= (float*)(base + 55771136);          // 7712*640 f32 (19.74 MB)
  float*    part  = (float*)(base + 55771136);          //   alias, max 16.6 MB
  float*    score = (float*)(base + 75513856);          // 246784 f32
  float*    fnorm = (float*)(base + 76500992);          // 7936 f32
  float*    gram  = (float*)(base + 76532736);          // 12800 f32
  float*    smat  = (float*)(base + 76583936);          // 1024 f32

  const int Tl[6]   = {127, 62, 30, 14, 6, 2};
  const int Poff[6] = {0, 127, 189, 219, 233, 239};

  // 0) unified operand prep (1 launch)
  prep_kernel<<<2048, 256, 0, stream>>>(
      video, fc_w, pw, words, conv_w, videoH, fcwH, pwH, wordsH, cwH);

  // 1) FC: M=8192 N=512 K=1024, grid (64,8) = 512 blocks
  g1p<128, 0><<<dim3(64, 8), 256, 0, stream>>>(
      videoH, fcwH, fc_b, fcoH, nullptr,
      8192, 8192, 0, 0, 1, 1024, 1024, 1024, 0, 0, 0, 512);

  // 2) conv0..5: uniform split-K + reduce. Grids >= 2 blocks/CU for 0-2.
  //    conv0: M=4064 (32 tiles), z=2, KLEN=1024 -> 512 blocks
  //    conv1: M=1984 (16), z=4, KLEN=512 -> 512
  //    conv2: M=960  (8),  z=8, KLEN=256 -> 512
  //    conv3: M=448  (4),  z=8 -> 256;  conv4: 2,8 -> 128;  conv5: 1,8 -> 64
  const int Ms[6]    = {4064, 1984, 960, 448, 192, 64};
  const int mbs[6]   = {32, 16, 8, 4, 2, 1};
  const int kSs[6]   = {2, 4, 8, 8, 8, 8};
  const int KLENs[6] = {1024, 512, 256, 256, 256, 256};
  const int Sin[6]   = {256, P_, P_, P_, P_, P_};      // SB of input view
  const int S0s[6]   = {0, 0, 127, 189, 219, 233};     // Poff[li-1]
  for (int li = 0; li < 6; ++li) {
    const _Float16* inA = (li == 0) ? fcoH : pyrH;
    g1p<128, 3><<<dim3(mbs[li], 8, kSs[li]), 256, 0, stream>>>(
        inA, cwH + (size_t)li * 512 * 2048, nullptr, nullptr, part,
        Ms[li], Tl[li], Sin[li], S0s[li], 2, 512, 2048, KLENs[li], Ms[li], 0, 0, 512);
    reduce_kernel<<<Ms[li] * 2, 256, 0, stream>>>(
        part, conv_b + li * 512, pyrH, kSs[li], Ms[li], Ms[li], Tl[li], Poff[li]);
  }

  // 3) pointwise projection: M=7712 N=512 K=512, grid (61,8) = 488 blocks
  g1p<128, 0><<<dim3(61, 8, 1), 256, 0, stream>>>(
      pyrH, pwH, pb, fallH, nullptr,
      B_ * P_, B_ * P_, 0, 0, 1, 512, 512, 512, 0, 0, 0, 512);

  // 4) norms, Gram, attention logits: N=640, grid (61,10) = 610 blocks
  fnorm_kernel<<<1928, 256, 0, stream>>>(fallH, fnorm);
  gram_kernel<<<Q_, 256, 0, stream>>>(words, gram);
  g1p<128, 2><<<dim3(61, 10, 1), 256, 0, stream>>>(
      fallH, wordsH, nullptr, nullptr, logits,
      B_ * P_, B_ * P_, 0, 0, 1, 512, 512, 512, 0, 0, 0, 640);

  // 5) softmax + cosine similarity (+ fused positive_map)
  sim_kernel<<<964, 256, 0, stream>>>(logits, gram, fnorm, score, out);

  // 6) NMS, loss
  nms_kernel<<<256, 256, 0, stream>>>(score, iou, lam, smat);
  loss_kernel<<<1, 1024, 0, stream>>>(smat, out);
}

// Round 10
// 204.329 us; speedup vs baseline: 1.2103x; 1.2103x over previous
//
#include <hip/hip_runtime.h>
#include <math.h>

// Problem constants
#define B_   32
#define T0_  256
#define J_   512
#define V_   1024
#define Q_   32
#define L_   20
#define P_   241
#define NEG_ (-1e9f)

typedef __attribute__((ext_vector_type(8))) _Float16 half8;
typedef __attribute__((ext_vector_type(4))) _Float16 half4v;
typedef __attribute__((ext_vector_type(4))) float f32x4;

// ---------------------------------------------------------------------------
// 1-pass fp16 MFMA GEMM: C[m][n] = sum_k AH[m][k] * BH[n][k]
// R8-proven config: tile 64x64, 4 waves (2x2), wave tile 32x32, KCH=128.
// LDS 34.8 KB -> 4 blocks/CU; grids sized >= 2-4 blocks/CU (R3/R5/R7/R9
// lesson: occupancy/TLP dominates; bigger tiles that halve the grid LOSE).
// Grid axes: blockIdx.x = COLUMN block (fastest-varying) so the 8-10 blocks
// sharing one A-row panel are dispatch-adjacent -> A re-reads hit L2/L3
// while resident. blockIdx.y = m-tile, blockIdx.z = split-K slice.
// A row view: arow = (m/TDIV)*SB + S0 + (m%TDIV)*TMUL, row stride ASTR
// (im2col for stride-2 conv: TMUL=2, ASTR=512).
// EPI: 0 = +bias -> fp16 (orow map); 1 = +bias+relu -> fp16;
//      2 = plain f32 (stride NS); 3 = f32 partials [z][MP][512].
// LDS row stride KCH+8 halves: uniform-8 bank access on b128 ops.
// Staging: static register arrays, fixed plane pointers (R6 scratch lesson).
// ---------------------------------------------------------------------------
template<int BM, int KCH, int EPI>
__global__ __launch_bounds__(256) void g1p(
    const _Float16* __restrict__ AH, const _Float16* __restrict__ BH,
    const float* __restrict__ bias,
    _Float16* __restrict__ outH, float* __restrict__ outF,
    int MROWS, int TDIV, int SB, int S0, int TMUL, int ASTR, int BSTR,
    int KLEN, int MP, int OSB, int OS0, int NS) {
  constexpr int FM = BM / 32;            // m-frags per wave
  constexpr int LSTR = KCH + 8;          // LDS row stride (halves)
  constexpr int TPRA = 256 / BM;         // threads per A row
  constexpr int AW = KCH / TPRA;         // halves per thread, A row
  constexpr int AU = AW / 8;             // half8 units per thread (A)
  constexpr int BW = KCH / 4;            // halves per thread, B row (64 rows)
  constexpr int BU = BW / 8;
  __shared__ _Float16 aS[BM * LSTR], bS[64 * LSTR];

  const int tid = threadIdx.x;
  const int n0 = blockIdx.x * 64, m0 = blockIdx.y * BM;   // x = column block
  const int k00 = blockIdx.z * KLEN;
  const int wave = tid >> 6, lane = tid & 63;
  const int wm = (wave >> 1) * (BM / 2), wn = (wave & 1) * 32;
  const int fr = lane & 15, fq = lane >> 4;

  const int arow = tid / TPRA;
  const int acol = (tid % TPRA) * AW;
  const int brow = tid >> 2, bcol = (tid & 3) * BW;

  const int gm = m0 + arow;
  const bool mval = gm < MROWS;
  const int b2g = gm / TDIV, t2g = gm - b2g * TDIV;
  const size_t aoff = (size_t)(b2g * SB + S0 + t2g * TMUL) * (size_t)ASTR;
  const size_t boff = (size_t)(n0 + brow) * (size_t)BSTR;

  f32x4 acc[FM][2];
  #pragma unroll
  for (int i = 0; i < FM; ++i) { acc[i][0] = (f32x4)0.f; acc[i][1] = (f32x4)0.f; }

  half8 z;
  #pragma unroll
  for (int j = 0; j < 8; ++j) z[j] = (_Float16)0.f;

  half8 rA[AU], rB[BU];
  auto load = [&](int it) {
    const int k = k00 + it * KCH;
    if (mval) {
      #pragma unroll
      for (int i = 0; i < AU; ++i)
        rA[i] = *reinterpret_cast<const half8*>(&AH[aoff + k + acol + i * 8]);
    } else {
      #pragma unroll
      for (int i = 0; i < AU; ++i) rA[i] = z;
    }
    #pragma unroll
    for (int i = 0; i < BU; ++i)
      rB[i] = *reinterpret_cast<const half8*>(&BH[boff + k + bcol + i * 8]);
  };

  load(0);
  const int NI = KLEN / KCH;

  for (int it = 0; it < NI; ++it) {
    __syncthreads();
    #pragma unroll
    for (int i = 0; i < AU; ++i)
      *reinterpret_cast<half8*>(&aS[arow * LSTR + acol + i * 8]) = rA[i];
    #pragma unroll
    for (int i = 0; i < BU; ++i)
      *reinterpret_cast<half8*>(&bS[brow * LSTR + bcol + i * 8]) = rB[i];
    __syncthreads();
    if (it + 1 < NI) load(it + 1);

    #pragma unroll
    for (int ks = 0; ks < KCH / 32; ++ks) {
      const int ko = ks * 32 + fq * 8;
      half8 a[FM], b[2];
      #pragma unroll
      for (int mt = 0; mt < FM; ++mt)
        a[mt] = *reinterpret_cast<const half8*>(&aS[(wm + mt * 16 + fr) * LSTR + ko]);
      b[0] = *reinterpret_cast<const half8*>(&bS[(wn + fr) * LSTR + ko]);
      b[1] = *reinterpret_cast<const half8*>(&bS[(wn + 16 + fr) * LSTR + ko]);
      #pragma unroll
      for (int mt = 0; mt < FM; ++mt) {
        acc[mt][0] = __builtin_amdgcn_mfma_f32_16x16x32_f16(a[mt], b[0], acc[mt][0], 0, 0, 0);
        acc[mt][1] = __builtin_amdgcn_mfma_f32_16x16x32_f16(a[mt], b[1], acc[mt][1], 0, 0, 0);
      }
    }
  }

  // Epilogue. C layout: col = lane&15 (n), row = fq*4 + reg (m).
  #pragma unroll
  for (int mt = 0; mt < FM; ++mt) {
    const int mB2 = m0 + wm + mt * 16 + fq * 4;
    #pragma unroll
    for (int nt = 0; nt < 2; ++nt) {
      const int n = n0 + wn + nt * 16 + fr;
      f32x4 c = acc[mt][nt];
      #pragma unroll
      for (int r = 0; r < 4; ++r) {
        const int m = mB2 + r;
        if (m < MROWS) {
          if (EPI == 3) {
            outF[((size_t)blockIdx.z * MP + m) * 512 + n] = c[r];
          } else if (EPI == 2) {
            outF[(size_t)m * NS + n] = c[r];
          } else {
            float x = c[r] + bias[n];
            if (EPI == 1) x = fmaxf(x, 0.f);
            const int bb2 = m / TDIV, tt2 = m - bb2 * TDIV;
            const int orow = bb2 * OSB + OS0 + tt2;
            outH[(size_t)orow * 512 + n] = (_Float16)x;
          }
        }
      }
    }
  }
}

// ---------------------------------------------------------------------------
// Split-K reduce: out(orow) = relu(sum_z part[z][m] + bias) -> fp16
// ---------------------------------------------------------------------------
__global__ __launch_bounds__(256) void reduce_kernel(
    const float* __restrict__ part, const float* __restrict__ bias,
    _Float16* __restrict__ outH,
    int kS, int MROWS, int MP, int Tl, int Poff) {
  int idx = blockIdx.x * 256 + threadIdx.x;
  if (idx >= MROWS * 512) return;
  int m = idx >> 9, n = idx & 511;
  float s = 0.f;
  for (int ks = 0; ks < kS; ++ks) s += part[((size_t)ks * MP + m) * 512 + n];
  float x = fmaxf(s + bias[n], 0.f);
  int b2 = m / Tl, t2 = m - b2 * Tl;
  int orow = b2 * P_ + Poff + t2;
  outH[(size_t)orow * 512 + n] = (_Float16)x;
}

// ---------------------------------------------------------------------------
// Unified prep: video cvt (2097152 f4), fc_w (131072), pw (65536),
// words (81920), conv_w repack (1572864 e-units). One launch, grid-stride.
// ---------------------------------------------------------------------------
#define PREP_C0 2097152
#define PREP_C1 2228224
#define PREP_C2 2293760
#define PREP_C3 2375680
#define PREP_C4 3948544
__global__ __launch_bounds__(256) void prep_kernel(
    const float* __restrict__ video, const float* __restrict__ fcw,
    const float* __restrict__ pw, const float* __restrict__ words,
    const float* __restrict__ cw,
    _Float16* __restrict__ videoH, _Float16* __restrict__ fcwH,
    _Float16* __restrict__ pwH, _Float16* __restrict__ wordsH,
    _Float16* __restrict__ cwH) {
  for (int u = blockIdx.x * 256 + threadIdx.x; u < PREP_C4; u += 2048 * 256) {
    if (u < PREP_C3) {
      const float* src; _Float16* dst; int off;
      if (u < PREP_C0)      { src = video; dst = videoH; off = u; }
      else if (u < PREP_C1) { src = fcw;   dst = fcwH;   off = u - PREP_C0; }
      else if (u < PREP_C2) { src = pw;    dst = pwH;    off = u - PREP_C1; }
      else                  { src = words; dst = wordsH; off = u - PREP_C2; }
      float4 v = *reinterpret_cast<const float4*>(&src[(size_t)off * 4]);
      half4v h;
      h[0] = (_Float16)v.x; h[1] = (_Float16)v.y;
      h[2] = (_Float16)v.z; h[3] = (_Float16)v.w;
      *reinterpret_cast<half4v*>(&dst[(size_t)off * 4]) = h;
    } else {
      int e = u - PREP_C3;
      float4 v = *reinterpret_cast<const float4*>(&cw[(size_t)e * 4]);
      int li = e >> 18, rem = e & 262143, o = rem >> 9, i = rem & 511;
      size_t rb = ((size_t)(li * 512 + o)) * 2048 + i;
      cwH[rb]        = (_Float16)v.x;
      cwH[rb + 512]  = (_Float16)v.y;
      cwH[rb + 1024] = (_Float16)v.z;
      cwH[rb + 1536] = (_Float16)v.w;
    }
  }
}

// ---------------------------------------------------------------------------
// Row L2 norms of f_all (fp16)
// ---------------------------------------------------------------------------
__global__ __launch_bounds__(256) void fnorm_kernel(
    const _Float16* __restrict__ fH, float* __restrict__ fn) {
  int gw = (blockIdx.x * 256 + threadIdx.x) >> 6;
  int lane = threadIdx.x & 63;
  if (gw >= B_ * P_) return;
  half8 h = *reinterpret_cast<const half8*>(&fH[(size_t)gw * 512 + lane * 8]);
  float s = 0.f;
  #pragma unroll
  for (int j = 0; j < 8; ++j) {
    float x = (float)h[j];
    s += x * x;
  }
  #pragma unroll
  for (int off = 32; off; off >>= 1) s += __shfl_xor(s, off);
  if (lane == 0) fn[gw] = sqrtf(s);
}

// ---------------------------------------------------------------------------
// Per-query word Gram matrices (f32 words input)
// ---------------------------------------------------------------------------
__global__ __launch_bounds__(256) void gram_kernel(
    const float* __restrict__ words, float* __restrict__ gram) {
  __shared__ float wsh[L_][513];
  int q = blockIdx.x, tid = threadIdx.x;
  for (int idx = tid; idx < L_ * 512; idx += 256)
    wsh[idx >> 9][idx & 511] = words[(size_t)q * L_ * J_ + idx];
  __syncthreads();
  for (int pr = tid; pr < L_ * L_; pr += 256) {
    int l = pr / L_, l2 = pr % L_;
    float sum = 0.f;
    for (int d = 0; d < J_; ++d) sum += wsh[l][d] * wsh[l2][d];
    gram[q * L_ * L_ + pr] = sum;
  }
}

// ---------------------------------------------------------------------------
// Softmax + cosine-sim epilogue per (q,b,p); positive_map fused (q==b rows).
// ---------------------------------------------------------------------------
__global__ __launch_bounds__(256) void sim_kernel(
    const float* __restrict__ logits, const float* __restrict__ gram,
    const float* __restrict__ fnorm, float* __restrict__ score,
    float* __restrict__ out) {
  int idx = blockIdx.x * 256 + threadIdx.x;
  if (idx >= Q_ * B_ * P_) return;
  int q = idx / (B_ * P_);
  int r = idx - q * (B_ * P_);
  const float* lg = &logits[(size_t)r * (Q_ * L_) + q * L_];
  float raw[L_], e[L_];
  float m = -1e30f;
  #pragma unroll
  for (int l = 0; l < L_; ++l) { raw[l] = lg[l]; m = fmaxf(m, raw[l]); }
  float s = 0.f;
  #pragma unroll
  for (int l = 0; l < L_; ++l) { e[l] = __expf(raw[l] - m); s += e[l]; }
  float inv = 1.f / s;
  float fvs = 0.f;
  #pragma unroll
  for (int l = 0; l < L_; ++l) fvs += e[l] * raw[l];
  fvs *= inv;
  const float* G = &gram[q * L_ * L_];
  float vn2 = 0.f;
  for (int l = 0; l < L_; ++l) {
    float acc = 0.f;
    #pragma unroll
    for (int l2 = 0; l2 < L_; ++l2) acc += e[l2] * G[l * L_ + l2];
    vn2 += e[l] * acc;
  }
  vn2 *= inv * inv;
  float fn = fnorm[r] + 1e-8f;
  float vn = sqrtf(fmaxf(vn2, 0.f)) + 1e-8f;
  float val = fvs / (fn * vn);
  score[idx] = val;
  int b = r / P_;
  if (b == q) out[1 + r] = val;   // positive_map (r = b*P + p)
}

// ---------------------------------------------------------------------------
// Greedy NMS
// ---------------------------------------------------------------------------
__global__ __launch_bounds__(256) void nms_kernel(
    const float* __restrict__ score, const float* __restrict__ iou,
    const float* __restrict__ lam, float* __restrict__ smat) {
  int wid = (blockIdx.x * 256 + threadIdx.x) >> 6;
  int lane = threadIdx.x & 63;
  if (wid >= Q_ * B_) return;
  const float* srow = &score[(size_t)wid * P_];
  float s[4];
  #pragma unroll
  for (int i = 0; i < 4; ++i) {
    int p = lane + 64 * i;
    s[i] = (p < P_) ? srow[p] : NEG_;
  }
  float lamv = lam[0];
  float acc = 0.f, wgt = 1.f;
  for (int k = 0; k < 5; ++k) {
    float bv = NEG_ * 2.f; int bi = 1 << 30;
    #pragma unroll
    for (int i = 0; i < 4; ++i) {
      int p = lane + 64 * i;
      if (s[i] > bv) { bv = s[i]; bi = p; }
    }
    for (int off = 32; off; off >>= 1) {
      float ov = __shfl_xor(bv, off);
      int oi = __shfl_xor(bi, off);
      if (ov > bv || (ov == bv && oi < bi)) { bv = ov; bi = oi; }
    }
    acc += bv * wgt;
    wgt *= lamv;
    const float* irow = &iou[(size_t)bi * P_];
    #pragma unroll
    for (int i = 0; i < 4; ++i) {
      int p = lane + 64 * i;
      if (p < P_ && irow[p] > 0.7f) s[i] = NEG_;
      if (p == bi) s[i] = NEG_;
    }
  }
  if (lane == 0) smat[wid] = acc * 0.2f;
}

// ---------------------------------------------------------------------------
// diag margin loss
// ---------------------------------------------------------------------------
__global__ __launch_bounds__(1024) void loss_kernel(
    const float* __restrict__ smat, float* __restrict__ out) {
  __shared__ float sm[B_][B_ + 1];
  __shared__ float red[16];
  int tid = threadIdx.x;
  sm[tid >> 5][tid & 31] = smat[tid];
  __syncthreads();
  int i = tid >> 5, j = tid & 31;
  float val = 0.f;
  if (i != j) {
    float sij = sm[i][j];
    val = fmaxf(0.f, 0.2f + sij - sm[i][i]) + fmaxf(0.f, 0.2f + sij - sm[j][j]);
  }
  #pragma unroll
  for (int off = 32; off; off >>= 1) val += __shfl_xor(val, off);
  if ((tid & 63) == 0) red[tid >> 6] = val;
  __syncthreads();
  if (tid == 0) {
    float t = 0.f;
    #pragma unroll
    for (int w = 0; w < 16; ++w) t += red[w];
    out[0] = t / 32.f;
  }
}

extern "C" void kernel_launch(void* const* d_in, const int* in_sizes, int n_in,
                              void* d_out, int out_size, void* d_ws, size_t ws_size,
                              hipStream_t stream) {
  const float* video  = (const float*)d_in[0];
  const float* words  = (const float*)d_in[1];
  // d_in[2] = w_masks: all-ones by construction, unused
  const float* lam    = (const float*)d_in[3];
  const float* iou    = (const float*)d_in[4];
  const float* fc_w   = (const float*)d_in[5];
  const float* fc_b   = (const float*)d_in[6];
  const float* conv_w = (const float*)d_in[7];
  const float* conv_b = (const float*)d_in[8];
  const float* pw     = (const float*)d_in[9];
  const float* pb     = (const float*)d_in[10];
  float* out = (float*)d_out;

  // Workspace layout (bytes) — R8 footprint (proven). Split-K partials
  // alias the logits region (written later).
  char* base = (char*)d_ws;
  _Float16* videoH= (_Float16*)(base + 0);              // 8192*1024 (16.78 MB)
  _Float16* fcoH  = (_Float16*)(base + 16777216);       // 8192*512  (8.39 MB)
  _Float16* pyrH  = (_Float16*)(base + 25165824);       // 7712*512  (7.90 MB)
  _Float16* fallH = (_Float16*)(base + 33062912);       // 7712*512  (7.90 MB)
  _Float16* cwH   = (_Float16*)(base + 40960000);       // 6*512*2048 (12.58 MB)
  _Float16* fcwH  = (_Float16*)(base + 53542912);       // 512*1024  (1.05 MB)
  _Float16* pwH   = (_Float16*)(base + 54591488);       // 512*512   (0.52 MB)
  _Float16* wordsH= (_Float16*)(base + 55115776);       // 32*20*512 (0.66 MB)
  float*    logits= (float*)(base + 55771136);          // 7712*640 f32 (19.74 MB)
  float*    part  = (float*)(base + 55771136);          //   alias, max 8.12 MB
  float*    score = (float*)(base + 75513856);          // 246784 f32
  float*    fnorm = (float*)(base + 76500992);          // 7936 f32
  float*    gram  = (float*)(base + 76532736);          // 12800 f32
  float*    smat  = (float*)(base + 76583936);          // 1024 f32

  const int Tl[6]   = {127, 62, 30, 14, 6, 2};
  const int Poff[6] = {0, 127, 189, 219, 233, 239};

  // 0) unified operand prep (1 launch)
  prep_kernel<<<2048, 256, 0, stream>>>(
      video, fc_w, pw, words, conv_w, videoH, fcwH, pwH, wordsH, cwH);

  // 1) FC: M=8192 N=512 K=1024, grid (8,128) = 1024 blocks (4/CU)
  g1p<64, 128, 0><<<dim3(8, 128), 256, 0, stream>>>(
      videoH, fcwH, fc_b, fcoH, nullptr,
      8192, 8192, 0, 0, 1, 1024, 1024, 1024, 0, 0, 0, 512);

  // 2) conv0: M=4064 K=2048, grid (8,64) = 512 blocks, direct write (no
  //    split-K — R9 lesson: the partials round-trip + launch cost loses)
  g1p<64, 128, 1><<<dim3(8, 64, 1), 256, 0, stream>>>(
      fcoH, cwH, conv_b, pyrH, nullptr,
      4064, 127, 256, 0, 2, 512, 2048, 2048, 0, P_, 0, 512);

  // 3) conv1..5: split-K partials (alias logits region) + reduce
  const int Ms[5]    = {1984, 960, 448, 192, 64};
  const int mbs[5]   = {31, 15, 7, 3, 1};
  const int kSs[5]   = {2, 4, 4, 8, 8};
  const int KLENs[5] = {1024, 512, 512, 256, 256};
  for (int i = 0; i < 5; ++i) {
    int li = i + 1;
    g1p<64, 128, 3><<<dim3(8, mbs[i], kSs[i]), 256, 0, stream>>>(
        pyrH, cwH + (size_t)li * 512 * 2048, nullptr, nullptr, part,
        Ms[i], Tl[li], P_, Poff[li - 1], 2, 512, 2048, KLENs[i], Ms[i], 0, 0, 512);
    reduce_kernel<<<Ms[i] * 2, 256, 0, stream>>>(
        part, conv_b + li * 512, pyrH, kSs[i], Ms[i], Ms[i], Tl[li], Poff[li]);
  }

  // 4) pointwise projection: M=7712 N=512 K=512, grid (8,121) = 968 blocks
  g1p<64, 128, 0><<<dim3(8, 121, 1), 256, 0, stream>>>(
      pyrH, pwH, pb, fallH, nullptr,
      B_ * P_, B_ * P_, 0, 0, 1, 512, 512, 512, 0, 0, 0, 512);

  // 5) norms, Gram, attention logits: N=640, grid (10,121) = 1210 blocks
  fnorm_kernel<<<1928, 256, 0, stream>>>(fallH, fnorm);
  gram_kernel<<<Q_, 256, 0, stream>>>(words, gram);
  g1p<64, 128, 2><<<dim3(10, 121, 1), 256, 0, stream>>>(
      fallH, wordsH, nullptr, nullptr, logits,
      B_ * P_, B_ * P_, 0, 0, 1, 512, 512, 512, 0, 0, 0, 640);

  // 6) softmax + cosine similarity (+ fused positive_map)
  sim_kernel<<<964, 256, 0, stream>>>(logits, gram, fnorm, score, out);

  // 7) NMS, loss
  nms_kernel<<<256, 256, 0, stream>>>(score, iou, lam, smat);
  loss_kernel<<<1, 1024, 0, stream>>>(smat, out);
}